// Round 17
// baseline (201.911 us; speedup 1.0000x reference)
//
#include <hip/hip_runtime.h>
#include <hip/hip_bf16.h>
#include <cmath>
#include <cstdint>

// Problem constants
#define B_ 4
#define T_ 2048
#define D_ 1024
#define H_ 16
#define HD_ 64
#define M_ (B_*T_)      // 8192 rows
#define NQKV_ 3072

// Q pre-scale: 1/sqrt(HD) * log2(e)  (softmax done in exp2 domain)
#define SCALE_Q 0.18033688011112042f

typedef float f32x4 __attribute__((ext_vector_type(4)));
typedef float f32x16 __attribute__((ext_vector_type(16)));
typedef __bf16 bf16x8 __attribute__((ext_vector_type(8)));
typedef __bf16 bf16x4 __attribute__((ext_vector_type(4)));

#define MFMA16(a, b, c) __builtin_amdgcn_mfma_f32_16x16x32_bf16((a), (b), (c), 0, 0, 0)
#define MFMA32(a, b, c) __builtin_amdgcn_mfma_f32_32x32x16_bf16((a), (b), (c), 0, 0, 0)

#if defined(__has_builtin)
#if __has_builtin(__builtin_amdgcn_global_load_lds)
#define HAVE_GLDS 1
#endif
#if __has_builtin(__builtin_amdgcn_permlane32_swap)
#define HAVE_PLSWAP 1
#endif
#endif

#ifdef HAVE_GLDS
#define GLDS16(g, l) __builtin_amdgcn_global_load_lds( \
    (const __attribute__((address_space(1))) void*)(g), \
    (__attribute__((address_space(3))) void*)(l), 16, 0, 0)
#endif

// guaranteed single-instruction 2^x (v_exp_f32; handles -inf -> 0)
__device__ inline float hexp2(float x) {
  float r; asm("v_exp_f32 %0, %1" : "=v"(r) : "v"(x)); return r;
}

__device__ inline uint32_t pack2bf(float a, float b) {
  union { __bf16 h[2]; uint32_t u; } x;
  x.h[0] = (__bf16)a; x.h[1] = (__bf16)b;
  return x.u;
}

// ---------------- f32 -> bf16 vectorized convert ----------------
__global__ __launch_bounds__(256) void k_cvt_bf16(const float4* __restrict__ in,
                                                  bf16x4* __restrict__ out, int n4) {
  int i = blockIdx.x * 256 + threadIdx.x;
  if (i >= n4) return;
  float4 v = in[i];
  bf16x4 o;
  o[0] = (__bf16)v.x; o[1] = (__bf16)v.y; o[2] = (__bf16)v.z; o[3] = (__bf16)v.w;
  out[i] = o;
}

// ---------------- f32 [R][C] -> bf16 [C][R] transpose+convert ----------------
__global__ __launch_bounds__(256) void k_transpose_cvt(const float* __restrict__ in,
                                                       __bf16* __restrict__ out,
                                                       int R, int C) {
  __shared__ float tile[64][65];
  int r0 = blockIdx.y * 64, c0 = blockIdx.x * 64;
#pragma unroll
  for (int i = 0; i < 16; ++i) {
    int e = threadIdx.x + i * 256;
    int lr = e >> 6, lc = e & 63;
    tile[lr][lc] = in[(size_t)(r0 + lr) * C + c0 + lc];
  }
  __syncthreads();
#pragma unroll
  for (int i = 0; i < 16; ++i) {
    int e = threadIdx.x + i * 256;
    int lc = e >> 6, lr = e & 63;
    out[(size_t)(c0 + lc) * R + r0 + lr] = (__bf16)tile[lr][lc];
  }
}

// ======== 128x192-tile QKV GEMM, BK=32 DOUBLE-BUFFERED (T3-minimum) ========
// C[M][3072] = A[M][1024] @ Bt[3072][1024]^T + bias, scatter -> Qb/Kb/Vt.
// r4-attn-proven loop: STAGE(buf^1, t+1) -> compute(buf) -> ONE barrier.
// Next-tile loads fly under current compute; barrier events halved.
// LDS 2x(8+12)KB = 40KB (same as r15) -> 4 blocks/CU kept.
// BK=32 rows are 64B: swizzle cc ^= (row>>1)&3 (2-way residual = free),
// staging source pre-swizzled to match (both-sides rule).
__global__ __launch_bounds__(256) void k_gemm_qkv(const __bf16* __restrict__ A,
                                                  const __bf16* __restrict__ Bt,
                                                  const float* __restrict__ bias,
                                                  __bf16* __restrict__ Qb,
                                                  __bf16* __restrict__ Kb,
                                                  __bf16* __restrict__ Vt) {
  __shared__ __bf16 lA[2][128 * 32];   // 2 x 8KB
  __shared__ __bf16 lB[2][192 * 32];   // 2 x 12KB
  const int tid = threadIdx.x;
  const int lane = tid & 63, w = tid >> 6;   // 4 waves
  const int wr = w >> 1, wc = w & 1;         // 2 M-groups x 2 N-groups
  const int r15 = lane & 15, rg = lane >> 4;
  const int mb = blockIdx.y, nb = blockIdx.x;
  const int K = D_;
  const int nt = K >> 5;   // 32

  const f32x4 zero = {0.f, 0.f, 0.f, 0.f};
  f32x4 acc[4][6];
#pragma unroll
  for (int m = 0; m < 4; ++m)
#pragma unroll
    for (int n = 0; n < 6; ++n) acc[m][n] = zero;

  const __bf16* Ab = A + (size_t)(mb * 128) * K;
  const __bf16* Bb = Bt + (size_t)(nb * 192) * K;

  // staging: A 128x32 = 512 chunks (2/thread); B 192x32 = 768 chunks (3/thread).
  // chunk c -> row = c>>2, cc = c&3; global src chunk g = cc ^ ((row>>1)&3).
  auto STAGE = [&](int bufi, int t) {
#pragma unroll
    for (int i = 0; i < 2; ++i) {
      const int c = tid + i * 256;
      const int r = c >> 2, g = (c & 3) ^ ((r >> 1) & 3);
#ifdef HAVE_GLDS
      GLDS16(Ab + (size_t)r * K + t * 32 + g * 8, &lA[bufi][c * 8]);
#else
      bf16x8 v = *(const bf16x8*)(Ab + (size_t)r * K + t * 32 + g * 8);
      *(bf16x8*)(&lA[bufi][c * 8]) = v;
#endif
    }
#pragma unroll
    for (int i = 0; i < 3; ++i) {
      const int c = tid + i * 256;
      const int r = c >> 2, g = (c & 3) ^ ((r >> 1) & 3);
#ifdef HAVE_GLDS
      GLDS16(Bb + (size_t)r * K + t * 32 + g * 8, &lB[bufi][c * 8]);
#else
      bf16x8 v = *(const bf16x8*)(Bb + (size_t)r * K + t * 32 + g * 8);
      *(bf16x8*)(&lB[bufi][c * 8]) = v;
#endif
    }
  };

  int buf = 0;
  STAGE(0, 0);
  __syncthreads();   // prologue loads landed

  for (int t = 0; t < nt; ++t) {
    if (t + 1 < nt) STAGE(buf ^ 1, t + 1);   // prefetch flies under compute
    bf16x8 af[4];
#pragma unroll
    for (int m = 0; m < 4; ++m) {
      const int row = wr * 64 + m * 16 + r15;
      const int cc = rg ^ ((row >> 1) & 3);
      af[m] = *(const bf16x8*)(&lA[buf][(row * 4 + cc) * 8]);
    }
#pragma unroll
    for (int n = 0; n < 6; ++n) {
      const int row = wc * 96 + n * 16 + r15;
      const int cc = rg ^ ((row >> 1) & 3);
      bf16x8 bfr = *(const bf16x8*)(&lB[buf][(row * 4 + cc) * 8]);
#pragma unroll
      for (int m = 0; m < 4; ++m)
        acc[m][n] = MFMA16(af[m], bfr, acc[m][n]);
    }
    __syncthreads();   // drains this iter's stage (vmcnt) + all reads of buf done
    buf ^= 1;
  }

  const int row0 = mb * 128 + wr * 64;
  const int col0 = nb * 192 + wc * 96;
#pragma unroll
  for (int m = 0; m < 4; ++m) {
#pragma unroll
    for (int n = 0; n < 6; ++n) {
      const int c = col0 + n * 16 + r15;
      const int r0 = row0 + m * 16 + rg * 4;          // j=0..3 -> r0..r0+3
      const int which = c >> 10, cc = c & 1023;
      const int b = r0 >> 11, t0 = r0 & 2047;         // same b for all 4 j
      float v[4];
#pragma unroll
      for (int j = 0; j < 4; ++j) v[j] = acc[m][n][j] + bias[c];
      if (which == 0) {
        int hh = cc >> 6, hd = cc & 63;
#pragma unroll
        for (int j = 0; j < 4; ++j)
          Qb[((size_t)(b * H_ + hh) * T_ + t0 + j) * HD_ + hd] = (__bf16)(v[j] * SCALE_Q);
      } else if (which == 1) {
        int hh = cc >> 6, hd = cc & 63;
#pragma unroll
        for (int j = 0; j < 4; ++j)
          Kb[((size_t)(b * H_ + hh) * T_ + t0 + j) * HD_ + hd] = (__bf16)v[j];
      } else {
        int hh = cc >> 6, hd = cc & 63;
        bf16x4 pk;
#pragma unroll
        for (int j = 0; j < 4; ++j) pk[j] = (__bf16)v[j];
        *(bf16x4*)(Vt + ((size_t)(b * H_ + hh) * HD_ + hd) * T_ + t0) = pk;
      }
    }
  }
}

// ---------------- bf16 GEMM 128x128, BK=32 DOUBLE-BUFFERED — proj matmul ----------------
// Same T3-minimum single-barrier loop. LDS 2x(8+8)=32KB (unchanged) -> 2 blk/CU.
__global__ __launch_bounds__(256) void k_gemm_proj(const __bf16* __restrict__ A,
                                                   const __bf16* __restrict__ Bt,
                                                   const float* __restrict__ bias,
                                                   float* __restrict__ Cf,
                                                   int K, int N) {
  __shared__ __bf16 lA[2][128 * 32];
  __shared__ __bf16 lB[2][128 * 32];
  const int tid = threadIdx.x;
  const int lane = tid & 63, w = tid >> 6;
  const int wr = w >> 1, wc = w & 1;
  const int r15 = lane & 15, rg = lane >> 4;
  const int mb = blockIdx.y, nb = blockIdx.x;
  const int nt = K >> 5;   // 32

  const f32x4 zero = {0.f, 0.f, 0.f, 0.f};
  f32x4 acc[4][4];
#pragma unroll
  for (int m = 0; m < 4; ++m)
#pragma unroll
    for (int n = 0; n < 4; ++n) acc[m][n] = zero;

  const __bf16* Ab = A + (size_t)(mb * 128) * K;
  const __bf16* Bb = Bt + (size_t)(nb * 128) * K;

  auto STAGE = [&](int bufi, int t) {
#pragma unroll
    for (int i = 0; i < 2; ++i) {
      const int c = tid + i * 256;
      const int r = c >> 2, g = (c & 3) ^ ((r >> 1) & 3);
#ifdef HAVE_GLDS
      GLDS16(Ab + (size_t)r * K + t * 32 + g * 8, &lA[bufi][c * 8]);
      GLDS16(Bb + (size_t)r * K + t * 32 + g * 8, &lB[bufi][c * 8]);
#else
      bf16x8 va = *(const bf16x8*)(Ab + (size_t)r * K + t * 32 + g * 8);
      bf16x8 vb = *(const bf16x8*)(Bb + (size_t)r * K + t * 32 + g * 8);
      *(bf16x8*)(&lA[bufi][c * 8]) = va;
      *(bf16x8*)(&lB[bufi][c * 8]) = vb;
#endif
    }
  };

  int buf = 0;
  STAGE(0, 0);
  __syncthreads();

  for (int t = 0; t < nt; ++t) {
    if (t + 1 < nt) STAGE(buf ^ 1, t + 1);
    bf16x8 af[4], bfr[4];
#pragma unroll
    for (int m = 0; m < 4; ++m) {
      const int row = wr * 64 + m * 16 + r15;
      const int cc = rg ^ ((row >> 1) & 3);
      af[m] = *(const bf16x8*)(&lA[buf][(row * 4 + cc) * 8]);
    }
#pragma unroll
    for (int n = 0; n < 4; ++n) {
      const int row = wc * 64 + n * 16 + r15;
      const int cc = rg ^ ((row >> 1) & 3);
      bfr[n] = *(const bf16x8*)(&lB[buf][(row * 4 + cc) * 8]);
    }
#pragma unroll
    for (int m = 0; m < 4; ++m)
#pragma unroll
      for (int n = 0; n < 4; ++n)
        acc[m][n] = MFMA16(af[m], bfr[n], acc[m][n]);
    __syncthreads();
    buf ^= 1;
  }

  const int row0 = mb * 128 + wr * 64;
  const int col0 = nb * 128 + wc * 64;
#pragma unroll
  for (int m = 0; m < 4; ++m)
#pragma unroll
    for (int n = 0; n < 4; ++n)
#pragma unroll
      for (int j = 0; j < 4; ++j) {
        int r = row0 + m * 16 + rg * 4 + j;
        int c = col0 + n * 16 + r15;
        Cf[(size_t)r * N + c] = acc[m][n][j] + bias[c];
      }
}

// ---------------- flash attention (causal), 4-wave block, LDS-staged K/V ----------------
// Round-16 kernel (81us, FETCH 34MB): bh-major grid (XCD-local K/V), paired
// supertiles, KVBLK=64 dbuf, fixed-max exp2 softmax, permlane32_swap, setprio.
__global__ __launch_bounds__(256) void k_attn(const __bf16* __restrict__ Qb,
                                              const __bf16* __restrict__ Kb,
                                              const __bf16* __restrict__ Vt,
                                              __bf16* __restrict__ Obuf) {
  __shared__ __bf16 lK[2][64 * 64];
  __shared__ __bf16 lV[2][64 * 64];
  const int tid = threadIdx.x;
  const int lane = tid & 63, w = tid >> 6;
  const int l31 = lane & 31, hi = lane >> 5;
  const int bh = blockIdx.x;            // XCD-local: bid%8 = bh%8
  const int b = bh >> 4, h = bh & 15;
  const __bf16* Qh = Qb + (size_t)bh * T_ * HD_;
  const __bf16* Kh = Kb + (size_t)bh * T_ * HD_;
  const __bf16* Vh = Vt + (size_t)bh * HD_ * T_;

  const int sRow0 = tid >> 3, sSw0 = (((tid) & 7) ^ (sRow0 & 7)) * 8;
  const int c1s = tid + 256;
  const int sRow1 = c1s >> 3, sSw1 = ((c1s & 7) ^ (sRow1 & 7)) * 8;

  auto STAGE = [&](int bufi, int kv0) {
#ifdef HAVE_GLDS
    GLDS16(Kh + (size_t)(kv0 + sRow0) * HD_ + sSw0, &lK[bufi][tid * 8]);
    GLDS16(Kh + (size_t)(kv0 + sRow1) * HD_ + sSw1, &lK[bufi][(tid + 256) * 8]);
    GLDS16(Vh + (size_t)sRow0 * T_ + kv0 + sSw0, &lV[bufi][tid * 8]);
    GLDS16(Vh + (size_t)sRow1 * T_ + kv0 + sSw1, &lV[bufi][(tid + 256) * 8]);
#else
    bf16x8 k0 = *(const bf16x8*)(Kh + (size_t)(kv0 + sRow0) * HD_ + sSw0);
    bf16x8 k1 = *(const bf16x8*)(Kh + (size_t)(kv0 + sRow1) * HD_ + sSw1);
    bf16x8 v0 = *(const bf16x8*)(Vh + (size_t)sRow0 * T_ + kv0 + sSw0);
    bf16x8 v1 = *(const bf16x8*)(Vh + (size_t)sRow1 * T_ + kv0 + sSw1);
    *(bf16x8*)(&lK[bufi][tid * 8]) = k0;
    *(bf16x8*)(&lK[bufi][(tid + 256) * 8]) = k1;
    *(bf16x8*)(&lV[bufi][tid * 8]) = v0;
    *(bf16x8*)(&lV[bufi][(tid + 256) * 8]) = v1;
#endif
  };

  int buf = 0;
  STAGE(0, 0);  // prologue: first tile of first half

  auto process_half = [&](int s, int nst, bool hasNext) {
    const int q0w = s * 128 + w * 32;
    bf16x8 qf[4];
#pragma unroll
    for (int ks = 0; ks < 4; ++ks)
      qf[ks] = *(const bf16x8*)(Qh + (size_t)(q0w + l31) * HD_ + ks * 16 + hi * 8);

    f32x16 o0, o1;
#pragma unroll
    for (int i = 0; i < 16; ++i) { o0[i] = 0.f; o1[i] = 0.f; }
    float lpart = 0.f;   // per-lane partial row-sum (cross-lane reduce deferred)

    for (int i = 0; i < nst; ++i) {
      const int kv0 = i * 64;
      if (i + 1 < nst) STAGE(buf ^ 1, (i + 1) * 64);
      else if (hasNext) STAGE(buf ^ 1, 0);

      if (kv0 <= q0w + 31) {  // wave-uniform: skip fully-masked tiles
        const bool masked = (kv0 + 63) > q0w;
        bf16x8 kf[2][4];
#pragma unroll
        for (int seg = 0; seg < 2; ++seg)
#pragma unroll
          for (int ks = 0; ks < 4; ++ks)
            kf[seg][ks] = *(const bf16x8*)(&lK[buf][(seg * 32 + l31) * 64 +
                                                   (((ks * 2 + hi) ^ (l31 & 7)) * 8)]);
        f32x16 s0, s1;
#pragma unroll
        for (int r = 0; r < 16; ++r) { s0[r] = 0.f; s1[r] = 0.f; }
        __builtin_amdgcn_s_setprio(1);
#pragma unroll
        for (int ks = 0; ks < 4; ++ks) s0 = MFMA32(kf[0][ks], qf[ks], s0);
#pragma unroll
        for (int ks = 0; ks < 4; ++ks) s1 = MFMA32(kf[1][ks], qf[ks], s1);
        __builtin_amdgcn_s_setprio(0);

        if (masked) {
#pragma unroll
          for (int r = 0; r < 16; ++r) {
            int rr = (r & 3) + 8 * (r >> 2) + 4 * hi;
            if (kv0 + rr > q0w + l31) s0[r] = -INFINITY;
            if (kv0 + 32 + rr > q0w + l31) s1[r] = -INFINITY;
          }
        }
        // fixed-max softmax: p = exp2(s), no max tracking (exp2(-inf)=0)
        float rs = 0.f;
#pragma unroll
        for (int r = 0; r < 16; ++r) {
          s0[r] = hexp2(s0[r]); s1[r] = hexp2(s1[r]);
          rs += s0[r] + s1[r];
        }
        lpart += rs;   // cross-lane shuffle deferred to epilogue

        bf16x8 vf[2][4];
#pragma unroll
        for (int dh = 0; dh < 2; ++dh)
#pragma unroll
          for (int ks = 0; ks < 4; ++ks)
            vf[dh][ks] = *(const bf16x8*)(&lV[buf][(dh * 32 + l31) * 64 +
                                                   (((ks * 2 + hi) ^ (l31 & 7)) * 8)]);

#pragma unroll
        for (int ks = 0; ks < 4; ++ks) {
          const f32x16& sv = (ks < 2) ? s0 : s1;
          const int off = (ks & 1) * 8;
          uint32_t w0 = pack2bf(sv[off + 0], sv[off + 1]);
          uint32_t w1 = pack2bf(sv[off + 2], sv[off + 3]);
          uint32_t w2 = pack2bf(sv[off + 4], sv[off + 5]);
          uint32_t w3 = pack2bf(sv[off + 6], sv[off + 7]);
          union { uint32_t u[4]; bf16x8 v; } pa;
#ifdef HAVE_PLSWAP
          auto rA = __builtin_amdgcn_permlane32_swap((int)w0, (int)w2, false, false);
          auto rB = __builtin_amdgcn_permlane32_swap((int)w1, (int)w3, false, false);
          pa.u[0] = (uint32_t)rA[0];
          pa.u[1] = (uint32_t)rB[0];
          pa.u[2] = (uint32_t)rA[1];
          pa.u[3] = (uint32_t)rB[1];
#else
          uint32_t sx = hi ? w0 : w2;
          uint32_t sy = hi ? w1 : w3;
          uint32_t px = (uint32_t)__shfl_xor((int)sx, 32, 64);
          uint32_t py = (uint32_t)__shfl_xor((int)sy, 32, 64);
          pa.u[0] = hi ? px : w0;
          pa.u[1] = hi ? py : w1;
          pa.u[2] = hi ? w2 : px;
          pa.u[3] = hi ? w3 : py;
#endif
          __builtin_amdgcn_s_setprio(1);
          o0 = MFMA32(pa.v, vf[0][ks], o0);
          o1 = MFMA32(pa.v, vf[1][ks], o1);
          __builtin_amdgcn_s_setprio(0);
        }
      }
      __syncthreads();
      buf ^= 1;
    }

    // epilogue: single cross-lane reduce, then row q' = rr(r,hi), col d = l31 (+32)
    float lrun = lpart + __shfl_xor(lpart, 32, 64);
#pragma unroll
    for (int r = 0; r < 16; ++r) {
      int rr = (r & 3) + 8 * (r >> 2) + 4 * hi;
      float inv = 1.0f / __shfl(lrun, rr, 64);
      int row = q0w + rr;
      __bf16* op = Obuf + (size_t)(b * T_ + row) * D_ + h * HD_ + l31;
      op[0]  = (__bf16)(o0[r] * inv);
      op[32] = (__bf16)(o1[r] * inv);
    }
  };

  const int sA = 15 - blockIdx.y;      // heavy half first
  const int sB = blockIdx.y;
  __syncthreads();                     // prologue stage visible
  process_half(sA, 2 * sA + 2, true);
  process_half(sB, 2 * sB + 2, false);
}

// ---------------- launcher ----------------
extern "C" void kernel_launch(void* const* d_in, const int* in_sizes, int n_in,
                              void* d_out, int out_size, void* d_ws, size_t ws_size,
                              hipStream_t stream) {
  const float* x      = (const float*)d_in[0];
  const float* W_qkv  = (const float*)d_in[1];
  const float* b_qkv  = (const float*)d_in[2];
  const float* W_proj = (const float*)d_in[3];
  const float* b_proj = (const float*)d_in[4];
  float* out = (float*)d_out;

  char* ws = (char*)d_ws;
  size_t o = 0;
  __bf16* xb     = (__bf16*)(ws + o); o += (size_t)M_ * D_ * 2;
  __bf16* wqkvt  = (__bf16*)(ws + o); o += (size_t)NQKV_ * D_ * 2;
  __bf16* wprojt = (__bf16*)(ws + o); o += (size_t)D_ * D_ * 2;
  __bf16* Qb     = (__bf16*)(ws + o); o += (size_t)M_ * D_ * 2;
  __bf16* Kb     = (__bf16*)(ws + o); o += (size_t)M_ * D_ * 2;
  __bf16* Vt     = (__bf16*)(ws + o); o += (size_t)M_ * D_ * 2;
  __bf16* Obuf   = (__bf16*)(ws + o); o += (size_t)M_ * D_ * 2;
  (void)ws_size; (void)in_sizes; (void)n_in; (void)out_size;

  k_cvt_bf16<<<(M_ * D_ / 4 + 255) / 256, 256, 0, stream>>>((const float4*)x, (bf16x4*)xb, M_ * D_ / 4);
  k_transpose_cvt<<<dim3(NQKV_ / 64, D_ / 64), 256, 0, stream>>>(W_qkv, wqkvt, D_, NQKV_);
  k_transpose_cvt<<<dim3(D_ / 64, D_ / 64), 256, 0, stream>>>(W_proj, wprojt, D_, D_);
  k_gemm_qkv<<<dim3(NQKV_ / 192, M_ / 128), 256, 0, stream>>>(xb, wqkvt, b_qkv, Qb, Kb, Vt);
  k_attn<<<dim3(B_ * H_, 8), 256, 0, stream>>>(Qb, Kb, Vt, Obuf);
  k_gemm_proj<<<dim3(D_ / 128, M_ / 128), 256, 0, stream>>>(Obuf, wprojt, b_proj, out, D_, D_);
}

// Round 18
// 183.818 us; speedup vs baseline: 1.0984x; 1.0984x over previous
//
#include <hip/hip_runtime.h>
#include <hip/hip_bf16.h>
#include <cmath>
#include <cstdint>

// Problem constants
#define B_ 4
#define T_ 2048
#define D_ 1024
#define H_ 16
#define HD_ 64
#define M_ (B_*T_)      // 8192 rows
#define NQKV_ 3072

// Q pre-scale: 1/sqrt(HD) * log2(e)  (softmax done in exp2 domain)
#define SCALE_Q 0.18033688011112042f

typedef float f32x4 __attribute__((ext_vector_type(4)));
typedef float f32x16 __attribute__((ext_vector_type(16)));
typedef __bf16 bf16x8 __attribute__((ext_vector_type(8)));
typedef __bf16 bf16x4 __attribute__((ext_vector_type(4)));

#define MFMA16(a, b, c) __builtin_amdgcn_mfma_f32_16x16x32_bf16((a), (b), (c), 0, 0, 0)
#define MFMA32(a, b, c) __builtin_amdgcn_mfma_f32_32x32x16_bf16((a), (b), (c), 0, 0, 0)

#if defined(__has_builtin)
#if __has_builtin(__builtin_amdgcn_global_load_lds)
#define HAVE_GLDS 1
#endif
#if __has_builtin(__builtin_amdgcn_permlane32_swap)
#define HAVE_PLSWAP 1
#endif
#endif

#ifdef HAVE_GLDS
#define GLDS16(g, l) __builtin_amdgcn_global_load_lds( \
    (const __attribute__((address_space(1))) void*)(g), \
    (__attribute__((address_space(3))) void*)(l), 16, 0, 0)
#endif

// guaranteed single-instruction 2^x (v_exp_f32; handles -inf -> 0)
__device__ inline float hexp2(float x) {
  float r; asm("v_exp_f32 %0, %1" : "=v"(r) : "v"(x)); return r;
}

__device__ inline uint32_t pack2bf(float a, float b) {
  union { __bf16 h[2]; uint32_t u; } x;
  x.h[0] = (__bf16)a; x.h[1] = (__bf16)b;
  return x.u;
}

// ---------------- f32 -> bf16 vectorized convert ----------------
__global__ __launch_bounds__(256) void k_cvt_bf16(const float4* __restrict__ in,
                                                  bf16x4* __restrict__ out, int n4) {
  int i = blockIdx.x * 256 + threadIdx.x;
  if (i >= n4) return;
  float4 v = in[i];
  bf16x4 o;
  o[0] = (__bf16)v.x; o[1] = (__bf16)v.y; o[2] = (__bf16)v.z; o[3] = (__bf16)v.w;
  out[i] = o;
}

// ---- fused weight transpose+convert: W_qkv [1024][3072] and W_proj [1024][1024] ----
// blockIdx.x < 48: W_qkv tile; else W_proj tile (x-48). Both transpose f32
// [R=1024][C] -> bf16 [C][1024].
__global__ __launch_bounds__(256) void k_transpose_cvt2(const float* __restrict__ Wqkv,
                                                        const float* __restrict__ Wproj,
                                                        __bf16* __restrict__ outQkv,
                                                        __bf16* __restrict__ outProj) {
  __shared__ float tile[64][65];
  const bool isProj = blockIdx.x >= (NQKV_ / 64);
  const float* in = isProj ? Wproj : Wqkv;
  __bf16* out = isProj ? outProj : outQkv;
  const int C = isProj ? D_ : NQKV_;
  const int cx = isProj ? (blockIdx.x - NQKV_ / 64) : blockIdx.x;
  int r0 = blockIdx.y * 64, c0 = cx * 64;
#pragma unroll
  for (int i = 0; i < 16; ++i) {
    int e = threadIdx.x + i * 256;
    int lr = e >> 6, lc = e & 63;
    tile[lr][lc] = in[(size_t)(r0 + lr) * C + c0 + lc];
  }
  __syncthreads();
#pragma unroll
  for (int i = 0; i < 16; ++i) {
    int e = threadIdx.x + i * 256;
    int lc = e >> 6, lr = e & 63;
    out[(size_t)(c0 + lc) * D_ + r0 + lr] = (__bf16)tile[lr][lc];
  }
}

// ======== 128x192-tile QKV GEMM, BK=64, 4 waves (round-15/16 proven) ========
// C[M][3072] = A[M][1024] @ Bt[3072][1024]^T + bias, scatter -> Qb/Kb/Vt.
// grid (16,64) = 1024 blocks = 4 blocks/CU. BK=64 both-sides XOR swizzle.
// Two-barrier K-loop (single-barrier dbuf REGRESSED in r17: __syncthreads
// drains the just-issued prefetch — m99/m100's structural stall).
__global__ __launch_bounds__(256) void k_gemm_qkv(const __bf16* __restrict__ A,
                                                  const __bf16* __restrict__ Bt,
                                                  const float* __restrict__ bias,
                                                  __bf16* __restrict__ Qb,
                                                  __bf16* __restrict__ Kb,
                                                  __bf16* __restrict__ Vt) {
  __shared__ __bf16 lA[128 * 64];   // 16KB
  __shared__ __bf16 lB[192 * 64];   // 24KB
  const int tid = threadIdx.x;
  const int lane = tid & 63, w = tid >> 6;   // 4 waves
  const int wr = w >> 1, wc = w & 1;         // 2 M-groups x 2 N-groups
  const int r15 = lane & 15, rg = lane >> 4;
  const int mb = blockIdx.y, nb = blockIdx.x;
  const int K = D_;
  const int nt = K >> 6;   // 16

  const f32x4 zero = {0.f, 0.f, 0.f, 0.f};
  f32x4 acc[4][6];
#pragma unroll
  for (int m = 0; m < 4; ++m)
#pragma unroll
    for (int n = 0; n < 6; ++n) acc[m][n] = zero;

  const __bf16* Ab = A + (size_t)(mb * 128) * K;
  const __bf16* Bb = Bt + (size_t)(nb * 192) * K;

  for (int t = 0; t < nt; ++t) {
    __syncthreads();
#pragma unroll
    for (int i = 0; i < 4; ++i) {     // A: 1024 chunks, 4/thread
      const int c = tid + i * 256;
      const int rA = c >> 3, g = (c & 7) ^ (rA & 7);
#ifdef HAVE_GLDS
      GLDS16(Ab + (size_t)rA * K + t * 64 + g * 8, &lA[c * 8]);
#else
      bf16x8 v = *(const bf16x8*)(Ab + (size_t)rA * K + t * 64 + g * 8);
      *(bf16x8*)(&lA[c * 8]) = v;
#endif
    }
#pragma unroll
    for (int i = 0; i < 6; ++i) {     // B: 1536 chunks, 6/thread
      const int c = tid + i * 256;
      const int rB = c >> 3, g = (c & 7) ^ (rB & 7);
#ifdef HAVE_GLDS
      GLDS16(Bb + (size_t)rB * K + t * 64 + g * 8, &lB[c * 8]);
#else
      bf16x8 v = *(const bf16x8*)(Bb + (size_t)rB * K + t * 64 + g * 8);
      *(bf16x8*)(&lB[c * 8]) = v;
#endif
    }
    __syncthreads();
#pragma unroll
    for (int ksub = 0; ksub < 2; ++ksub) {
      const int cc = (ksub * 4 + rg) ^ (r15 & 7);
      bf16x8 af[4];
#pragma unroll
      for (int m = 0; m < 4; ++m) {
        const int row = wr * 64 + m * 16 + r15;
        af[m] = *(const bf16x8*)(&lA[(row * 8 + cc) * 8]);
      }
#pragma unroll
      for (int n = 0; n < 6; ++n) {
        const int row = wc * 96 + n * 16 + r15;
        bf16x8 bfr = *(const bf16x8*)(&lB[(row * 8 + cc) * 8]);
#pragma unroll
        for (int m = 0; m < 4; ++m)
          acc[m][n] = MFMA16(af[m], bfr, acc[m][n]);
      }
    }
  }

  const int row0 = mb * 128 + wr * 64;
  const int col0 = nb * 192 + wc * 96;
#pragma unroll
  for (int m = 0; m < 4; ++m) {
#pragma unroll
    for (int n = 0; n < 6; ++n) {
      const int c = col0 + n * 16 + r15;
      const int r0 = row0 + m * 16 + rg * 4;          // j=0..3 -> r0..r0+3
      const int which = c >> 10, cc = c & 1023;
      const int b = r0 >> 11, t0 = r0 & 2047;         // same b for all 4 j
      float v[4];
#pragma unroll
      for (int j = 0; j < 4; ++j) v[j] = acc[m][n][j] + bias[c];
      if (which == 0) {
        int hh = cc >> 6, hd = cc & 63;
#pragma unroll
        for (int j = 0; j < 4; ++j)
          Qb[((size_t)(b * H_ + hh) * T_ + t0 + j) * HD_ + hd] = (__bf16)(v[j] * SCALE_Q);
      } else if (which == 1) {
        int hh = cc >> 6, hd = cc & 63;
#pragma unroll
        for (int j = 0; j < 4; ++j)
          Kb[((size_t)(b * H_ + hh) * T_ + t0 + j) * HD_ + hd] = (__bf16)v[j];
      } else {
        int hh = cc >> 6, hd = cc & 63;
        bf16x4 pk;
#pragma unroll
        for (int j = 0; j < 4; ++j) pk[j] = (__bf16)v[j];
        *(bf16x4*)(Vt + ((size_t)(b * H_ + hh) * HD_ + hd) * T_ + t0) = pk;
      }
    }
  }
}

// ---------------- bf16 GEMM 128x128, BK=64 — proj matmul (round-14 proven) ----------------
__global__ __launch_bounds__(256) void k_gemm_proj(const __bf16* __restrict__ A,
                                                   const __bf16* __restrict__ Bt,
                                                   const float* __restrict__ bias,
                                                   float* __restrict__ Cf,
                                                   int K, int N) {
  __shared__ __bf16 lA[128 * 64];   // 16KB
  __shared__ __bf16 lB[128 * 64];   // 16KB
  const int tid = threadIdx.x;
  const int lane = tid & 63, w = tid >> 6;
  const int wr = w >> 1, wc = w & 1;
  const int r15 = lane & 15, rg = lane >> 4;
  const int mb = blockIdx.y, nb = blockIdx.x;
  const int nt = K >> 6;   // 16

  const f32x4 zero = {0.f, 0.f, 0.f, 0.f};
  f32x4 acc[4][4];
#pragma unroll
  for (int m = 0; m < 4; ++m)
#pragma unroll
    for (int n = 0; n < 4; ++n) acc[m][n] = zero;

  const __bf16* Ab = A + (size_t)(mb * 128) * K;
  const __bf16* Bb = Bt + (size_t)(nb * 128) * K;

  for (int t = 0; t < nt; ++t) {
    __syncthreads();
#pragma unroll
    for (int i = 0; i < 4; ++i) {     // A: 1024 chunks, 4/thread
      const int c = tid + i * 256;
      const int rA = c >> 3, g = (c & 7) ^ (rA & 7);
#ifdef HAVE_GLDS
      GLDS16(Ab + (size_t)rA * K + t * 64 + g * 8, &lA[c * 8]);
#else
      bf16x8 v = *(const bf16x8*)(Ab + (size_t)rA * K + t * 64 + g * 8);
      *(bf16x8*)(&lA[c * 8]) = v;
#endif
    }
#pragma unroll
    for (int i = 0; i < 4; ++i) {     // B: 1024 chunks, 4/thread
      const int c = tid + i * 256;
      const int rB = c >> 3, g = (c & 7) ^ (rB & 7);
#ifdef HAVE_GLDS
      GLDS16(Bb + (size_t)rB * K + t * 64 + g * 8, &lB[c * 8]);
#else
      bf16x8 v = *(const bf16x8*)(Bb + (size_t)rB * K + t * 64 + g * 8);
      *(bf16x8*)(&lB[c * 8]) = v;
#endif
    }
    __syncthreads();
#pragma unroll
    for (int ksub = 0; ksub < 2; ++ksub) {
      bf16x8 af[4], bfr[4];
#pragma unroll
      for (int m = 0; m < 4; ++m) {
        const int row = wr * 64 + m * 16 + r15;
        const int cc = (ksub * 4 + rg) ^ (r15 & 7);
        af[m] = *(const bf16x8*)(&lA[(row * 8 + cc) * 8]);
      }
#pragma unroll
      for (int n = 0; n < 4; ++n) {
        const int row = wc * 64 + n * 16 + r15;
        const int cc = (ksub * 4 + rg) ^ (r15 & 7);
        bfr[n] = *(const bf16x8*)(&lB[(row * 8 + cc) * 8]);
      }
#pragma unroll
      for (int m = 0; m < 4; ++m)
#pragma unroll
        for (int n = 0; n < 4; ++n)
          acc[m][n] = MFMA16(af[m], bfr[n], acc[m][n]);
    }
  }

  const int row0 = mb * 128 + wr * 64;
  const int col0 = nb * 128 + wc * 64;
#pragma unroll
  for (int m = 0; m < 4; ++m)
#pragma unroll
    for (int n = 0; n < 4; ++n)
#pragma unroll
      for (int j = 0; j < 4; ++j) {
        int r = row0 + m * 16 + rg * 4 + j;
        int c = col0 + n * 16 + r15;
        Cf[(size_t)r * N + c] = acc[m][n][j] + bias[c];
      }
}

// ---------------- flash attention (causal), 4-wave block, LDS-staged K/V ----------------
// Round-16 kernel (81us, FETCH 34MB): bh-major grid (XCD-local K/V), paired
// supertiles, KVBLK=64 dbuf, fixed-max exp2 softmax, permlane32_swap, setprio.
__global__ __launch_bounds__(256) void k_attn(const __bf16* __restrict__ Qb,
                                              const __bf16* __restrict__ Kb,
                                              const __bf16* __restrict__ Vt,
                                              __bf16* __restrict__ Obuf) {
  __shared__ __bf16 lK[2][64 * 64];
  __shared__ __bf16 lV[2][64 * 64];
  const int tid = threadIdx.x;
  const int lane = tid & 63, w = tid >> 6;
  const int l31 = lane & 31, hi = lane >> 5;
  const int bh = blockIdx.x;            // XCD-local: bid%8 = bh%8
  const int b = bh >> 4, h = bh & 15;
  const __bf16* Qh = Qb + (size_t)bh * T_ * HD_;
  const __bf16* Kh = Kb + (size_t)bh * T_ * HD_;
  const __bf16* Vh = Vt + (size_t)bh * HD_ * T_;

  const int sRow0 = tid >> 3, sSw0 = (((tid) & 7) ^ (sRow0 & 7)) * 8;
  const int c1s = tid + 256;
  const int sRow1 = c1s >> 3, sSw1 = ((c1s & 7) ^ (sRow1 & 7)) * 8;

  auto STAGE = [&](int bufi, int kv0) {
#ifdef HAVE_GLDS
    GLDS16(Kh + (size_t)(kv0 + sRow0) * HD_ + sSw0, &lK[bufi][tid * 8]);
    GLDS16(Kh + (size_t)(kv0 + sRow1) * HD_ + sSw1, &lK[bufi][(tid + 256) * 8]);
    GLDS16(Vh + (size_t)sRow0 * T_ + kv0 + sSw0, &lV[bufi][tid * 8]);
    GLDS16(Vh + (size_t)sRow1 * T_ + kv0 + sSw1, &lV[bufi][(tid + 256) * 8]);
#else
    bf16x8 k0 = *(const bf16x8*)(Kh + (size_t)(kv0 + sRow0) * HD_ + sSw0);
    bf16x8 k1 = *(const bf16x8*)(Kh + (size_t)(kv0 + sRow1) * HD_ + sSw1);
    bf16x8 v0 = *(const bf16x8*)(Vh + (size_t)sRow0 * T_ + kv0 + sSw0);
    bf16x8 v1 = *(const bf16x8*)(Vh + (size_t)sRow1 * T_ + kv0 + sSw1);
    *(bf16x8*)(&lK[bufi][tid * 8]) = k0;
    *(bf16x8*)(&lK[bufi][(tid + 256) * 8]) = k1;
    *(bf16x8*)(&lV[bufi][tid * 8]) = v0;
    *(bf16x8*)(&lV[bufi][(tid + 256) * 8]) = v1;
#endif
  };

  int buf = 0;
  STAGE(0, 0);  // prologue: first tile of first half

  auto process_half = [&](int s, int nst, bool hasNext) {
    const int q0w = s * 128 + w * 32;
    bf16x8 qf[4];
#pragma unroll
    for (int ks = 0; ks < 4; ++ks)
      qf[ks] = *(const bf16x8*)(Qh + (size_t)(q0w + l31) * HD_ + ks * 16 + hi * 8);

    f32x16 o0, o1;
#pragma unroll
    for (int i = 0; i < 16; ++i) { o0[i] = 0.f; o1[i] = 0.f; }
    float lpart = 0.f;   // per-lane partial row-sum (cross-lane reduce deferred)

    for (int i = 0; i < nst; ++i) {
      const int kv0 = i * 64;
      if (i + 1 < nst) STAGE(buf ^ 1, (i + 1) * 64);
      else if (hasNext) STAGE(buf ^ 1, 0);

      if (kv0 <= q0w + 31) {  // wave-uniform: skip fully-masked tiles
        const bool masked = (kv0 + 63) > q0w;
        bf16x8 kf[2][4];
#pragma unroll
        for (int seg = 0; seg < 2; ++seg)
#pragma unroll
          for (int ks = 0; ks < 4; ++ks)
            kf[seg][ks] = *(const bf16x8*)(&lK[buf][(seg * 32 + l31) * 64 +
                                                   (((ks * 2 + hi) ^ (l31 & 7)) * 8)]);
        f32x16 s0, s1;
#pragma unroll
        for (int r = 0; r < 16; ++r) { s0[r] = 0.f; s1[r] = 0.f; }
        __builtin_amdgcn_s_setprio(1);
#pragma unroll
        for (int ks = 0; ks < 4; ++ks) s0 = MFMA32(kf[0][ks], qf[ks], s0);
#pragma unroll
        for (int ks = 0; ks < 4; ++ks) s1 = MFMA32(kf[1][ks], qf[ks], s1);
        __builtin_amdgcn_s_setprio(0);

        if (masked) {
#pragma unroll
          for (int r = 0; r < 16; ++r) {
            int rr = (r & 3) + 8 * (r >> 2) + 4 * hi;
            if (kv0 + rr > q0w + l31) s0[r] = -INFINITY;
            if (kv0 + 32 + rr > q0w + l31) s1[r] = -INFINITY;
          }
        }
        // fixed-max softmax: p = exp2(s), no max tracking (exp2(-inf)=0)
        float rs = 0.f;
#pragma unroll
        for (int r = 0; r < 16; ++r) {
          s0[r] = hexp2(s0[r]); s1[r] = hexp2(s1[r]);
          rs += s0[r] + s1[r];
        }
        lpart += rs;   // cross-lane shuffle deferred to epilogue

        bf16x8 vf[2][4];
#pragma unroll
        for (int dh = 0; dh < 2; ++dh)
#pragma unroll
          for (int ks = 0; ks < 4; ++ks)
            vf[dh][ks] = *(const bf16x8*)(&lV[buf][(dh * 32 + l31) * 64 +
                                                   (((ks * 2 + hi) ^ (l31 & 7)) * 8)]);

#pragma unroll
        for (int ks = 0; ks < 4; ++ks) {
          const f32x16& sv = (ks < 2) ? s0 : s1;
          const int off = (ks & 1) * 8;
          uint32_t w0 = pack2bf(sv[off + 0], sv[off + 1]);
          uint32_t w1 = pack2bf(sv[off + 2], sv[off + 3]);
          uint32_t w2 = pack2bf(sv[off + 4], sv[off + 5]);
          uint32_t w3 = pack2bf(sv[off + 6], sv[off + 7]);
          union { uint32_t u[4]; bf16x8 v; } pa;
#ifdef HAVE_PLSWAP
          auto rA = __builtin_amdgcn_permlane32_swap((int)w0, (int)w2, false, false);
          auto rB = __builtin_amdgcn_permlane32_swap((int)w1, (int)w3, false, false);
          pa.u[0] = (uint32_t)rA[0];
          pa.u[1] = (uint32_t)rB[0];
          pa.u[2] = (uint32_t)rA[1];
          pa.u[3] = (uint32_t)rB[1];
#else
          uint32_t sx = hi ? w0 : w2;
          uint32_t sy = hi ? w1 : w3;
          uint32_t px = (uint32_t)__shfl_xor((int)sx, 32, 64);
          uint32_t py = (uint32_t)__shfl_xor((int)sy, 32, 64);
          pa.u[0] = hi ? px : w0;
          pa.u[1] = hi ? py : w1;
          pa.u[2] = hi ? w2 : px;
          pa.u[3] = hi ? w3 : py;
#endif
          __builtin_amdgcn_s_setprio(1);
          o0 = MFMA32(pa.v, vf[0][ks], o0);
          o1 = MFMA32(pa.v, vf[1][ks], o1);
          __builtin_amdgcn_s_setprio(0);
        }
      }
      __syncthreads();
      buf ^= 1;
    }

    // epilogue: single cross-lane reduce, then row q' = rr(r,hi), col d = l31 (+32)
    float lrun = lpart + __shfl_xor(lpart, 32, 64);
#pragma unroll
    for (int r = 0; r < 16; ++r) {
      int rr = (r & 3) + 8 * (r >> 2) + 4 * hi;
      float inv = 1.0f / __shfl(lrun, rr, 64);
      int row = q0w + rr;
      __bf16* op = Obuf + (size_t)(b * T_ + row) * D_ + h * HD_ + l31;
      op[0]  = (__bf16)(o0[r] * inv);
      op[32] = (__bf16)(o1[r] * inv);
    }
  };

  const int sA = 15 - blockIdx.y;      // heavy half first
  const int sB = blockIdx.y;
  __syncthreads();                     // prologue stage visible
  process_half(sA, 2 * sA + 2, true);
  process_half(sB, 2 * sB + 2, false);
}

// ---------------- launcher ----------------
extern "C" void kernel_launch(void* const* d_in, const int* in_sizes, int n_in,
                              void* d_out, int out_size, void* d_ws, size_t ws_size,
                              hipStream_t stream) {
  const float* x      = (const float*)d_in[0];
  const float* W_qkv  = (const float*)d_in[1];
  const float* b_qkv  = (const float*)d_in[2];
  const float* W_proj = (const float*)d_in[3];
  const float* b_proj = (const float*)d_in[4];
  float* out = (float*)d_out;

  char* ws = (char*)d_ws;
  size_t o = 0;
  __bf16* xb     = (__bf16*)(ws + o); o += (size_t)M_ * D_ * 2;
  __bf16* wqkvt  = (__bf16*)(ws + o); o += (size_t)NQKV_ * D_ * 2;
  __bf16* wprojt = (__bf16*)(ws + o); o += (size_t)D_ * D_ * 2;
  __bf16* Qb     = (__bf16*)(ws + o); o += (size_t)M_ * D_ * 2;
  __bf16* Kb     = (__bf16*)(ws + o); o += (size_t)M_ * D_ * 2;
  __bf16* Vt     = (__bf16*)(ws + o); o += (size_t)M_ * D_ * 2;
  __bf16* Obuf   = (__bf16*)(ws + o); o += (size_t)M_ * D_ * 2;
  (void)ws_size; (void)in_sizes; (void)n_in; (void)out_size;

  k_cvt_bf16<<<(M_ * D_ / 4 + 255) / 256, 256, 0, stream>>>((const float4*)x, (bf16x4*)xb, M_ * D_ / 4);
  k_transpose_cvt2<<<dim3(NQKV_ / 64 + D_ / 64, D_ / 64), 256, 0, stream>>>(W_qkv, W_proj, wqkvt, wprojt);
  k_gemm_qkv<<<dim3(NQKV_ / 192, M_ / 128), 256, 0, stream>>>(xb, wqkvt, b_qkv, Qb, Kb, Vt);
  k_attn<<<dim3(B_ * H_, 8), 256, 0, stream>>>(Qb, Kb, Vt, Obuf);
  k_gemm_proj<<<dim3(D_ / 128, M_ / 128), 256, 0, stream>>>(Obuf, wprojt, b_proj, out, D_, D_);
}